// Round 4
// baseline (253.789 us; speedup 1.0000x reference)
//
#include <hip/hip_runtime.h>

// Problem constants (from setup_inputs)
#define BB   4
#define NN   5
#define JJ   15
#define HHH  128
#define WHH  240
#define CBX  80
#define CBY  80
#define CBZ  20
#define PP   (CBX*CBY*CBZ)          // 128000
#define IMGW 960.0f
#define IMGH 512.0f
#define JGRP 5                      // joint groups (blockIdx.y)
#define JPER 3                      // joints per group (5*3 = 15)

__global__ __launch_bounds__(256) void project_kernel(
    const float* __restrict__ hm,      // [N,B,J,H,W]
    const float* __restrict__ Rm,      // [B,N,3,3]
    const float* __restrict__ Tv,      // [B,N,3]
    const float* __restrict__ fv,      // [B,N,2]
    const float* __restrict__ cv,      // [B,N,2]
    const float* __restrict__ trans,   // [B,N,2,3]
    const float* __restrict__ whv,     // [B,N,2]
    const float* __restrict__ gcv,     // [B,3]
    float* __restrict__ out)           // fused [B,J,P] then grids [B,P,3]
{
    int t = blockIdx.x * blockDim.x + threadIdx.x;
    if (t >= BB * PP) return;
    int jg = blockIdx.y;               // 0..4, handles joints jg*3 .. jg*3+2
    int b = t / PP;
    int p = t - b * PP;
    int ix  = p / (CBY * CBZ);
    int rem = p - ix * (CBY * CBZ);
    int iy  = rem / CBZ;
    int iz  = rem - iy * CBZ;

    const float stx = 8000.0f / (CBX - 1);
    const float sty = 8000.0f / (CBY - 1);
    const float stz = 2000.0f / (CBZ - 1);
    float gx = -4000.0f + (float)ix * stx + gcv[b * 3 + 0];
    float gy = -4000.0f + (float)iy * sty + gcv[b * 3 + 1];
    float gz = -1000.0f + (float)iz * stz + gcv[b * 3 + 2];

    // grids output (second tuple element) — written once (jg==0)
    if (jg == 0) {
        float* grids_out = out + (size_t)BB * JJ * PP;
        size_t gb = (size_t)(b * PP + p) * 3;
        grids_out[gb + 0] = gx;
        grids_out[gb + 1] = gy;
        grids_out[gb + 2] = gz;
    }

    float w00[NN], w10[NN], w01[NN], w11[NN];
    int   i00[NN], i10[NN], i01[NN], i11[NN];
    float sumb = 0.0f;

    #pragma unroll
    for (int n = 0; n < NN; ++n) {
        int bn = b * NN + n;
        const float* R = Rm + bn * 9;
        float dx = gx - Tv[bn * 3 + 0];
        float dy = gy - Tv[bn * 3 + 1];
        float dz = gz - Tv[bn * 3 + 2];
        float cx = R[0] * dx + R[1] * dy + R[2] * dz;
        float cy = R[3] * dx + R[4] * dy + R[5] * dz;
        float cz = R[6] * dx + R[7] * dy + R[8] * dz;
        float inv = 1.0f / cz;
        float px = cx * inv * fv[bn * 2 + 0] + cv[bn * 2 + 0];
        float py = cy * inv * fv[bn * 2 + 1] + cv[bn * 2 + 1];
        float w = whv[bn * 2 + 0], h = whv[bn * 2 + 1];
        float bound = (px >= 0.0f && py >= 0.0f && px < w && py < h) ? 1.0f : 0.0f;
        float mwh = fmaxf(w, h);
        px = fminf(fmaxf(px, -1.0f), mwh);
        py = fminf(fmaxf(py, -1.0f), mwh);
        const float* tr = trans + bn * 6;
        float tx = tr[0] * px + tr[1] * py + tr[2];
        float ty = tr[3] * px + tr[4] * py + tr[5];
        tx *= (float)WHH / IMGW;   // 0.25
        ty *= (float)HHH / IMGH;   // 0.25
        float sgx = tx / (float)(WHH - 1) * 2.0f - 1.0f;
        float sgy = ty / (float)(HHH - 1) * 2.0f - 1.0f;
        sgx = fminf(fmaxf(sgx, -1.1f), 1.1f);
        sgy = fminf(fmaxf(sgy, -1.1f), 1.1f);
        float xx = (sgx + 1.0f) * 0.5f * (float)(WHH - 1);
        float yy = (sgy + 1.0f) * 0.5f * (float)(HHH - 1);
        float x0f = floorf(xx), y0f = floorf(yy);
        float wx = xx - x0f, wy = yy - y0f;
        int x0 = (int)x0f, y0 = (int)y0f;
        int x1 = x0 + 1, y1 = y0 + 1;
        float vx0 = (x0 >= 0 && x0 <= WHH - 1) ? 1.0f : 0.0f;
        float vx1 = (x1 >= 0 && x1 <= WHH - 1) ? 1.0f : 0.0f;
        float vy0 = (y0 >= 0 && y0 <= HHH - 1) ? 1.0f : 0.0f;
        float vy1 = (y1 >= 0 && y1 <= HHH - 1) ? 1.0f : 0.0f;
        int xc0 = min(max(x0, 0), WHH - 1);
        int xc1 = min(max(x1, 0), WHH - 1);
        int yc0 = min(max(y0, 0), HHH - 1);
        int yc1 = min(max(y1, 0), HHH - 1);
        // fold bound into the weights: cube_n * bound_n == sum of (w*bound)*img
        w00[n] = bound * vx0 * vy0 * (1.0f - wx) * (1.0f - wy);
        w10[n] = bound * vx1 * vy0 * wx * (1.0f - wy);
        w01[n] = bound * vx0 * vy1 * (1.0f - wx) * wy;
        w11[n] = bound * vx1 * vy1 * wx * wy;
        i00[n] = yc0 * WHH + xc0;
        i10[n] = yc0 * WHH + xc1;
        i01[n] = yc1 * WHH + xc0;
        i11[n] = yc1 * WHH + xc1;
        sumb += bound;
    }

    float denom = 1.0f / (sumb + 1e-6f);
    size_t outb = (size_t)b * JJ * PP + p;

    #pragma unroll
    for (int k = 0; k < JPER; ++k) {
        int j = jg * JPER + k;
        float acc = 0.0f;
        #pragma unroll
        for (int n = 0; n < NN; ++n) {
            const float* img = hm + (size_t)((n * BB + b) * JJ + j) * (HHH * WHH);
            acc += w00[n] * img[i00[n]] + w10[n] * img[i10[n]]
                 + w01[n] * img[i01[n]] + w11[n] * img[i11[n]];
        }
        float v = acc * denom;
        v = fminf(fmaxf(v, 0.0f), 1.0f);
        out[outb + (size_t)j * PP] = v;
    }
}

extern "C" void kernel_launch(void* const* d_in, const int* in_sizes, int n_in,
                              void* d_out, int out_size, void* d_ws, size_t ws_size,
                              hipStream_t stream) {
    const float* hm    = (const float*)d_in[0];
    const float* Rm    = (const float*)d_in[1];
    const float* Tv    = (const float*)d_in[2];
    const float* fv    = (const float*)d_in[3];
    const float* cv    = (const float*)d_in[4];
    const float* trans = (const float*)d_in[5];
    const float* whv   = (const float*)d_in[6];
    const float* gcv   = (const float*)d_in[7];
    float* out = (float*)d_out;

    int total = BB * PP;
    int block = 256;
    dim3 grid((total + block - 1) / block, JGRP);
    project_kernel<<<grid, block, 0, stream>>>(hm, Rm, Tv, fv, cv, trans, whv, gcv, out);
}

// Round 5
// 173.150 us; speedup vs baseline: 1.4657x; 1.4657x over previous
//
#include <hip/hip_runtime.h>

// Problem constants (from setup_inputs)
#define BB   4
#define NN   5
#define JJ   15
#define HHH  128
#define WHH  240
#define CBX  80
#define CBY  80
#define CBZ  20
#define PP   (CBX*CBY*CBZ)          // 128000
#define HW   (HHH*WHH)              // 30720
#define IMGW 960.0f
#define IMGH 512.0f

__global__ __launch_bounds__(256) void project_kernel(
    const float* __restrict__ hm,      // [N,B,J,H,W]
    const float* __restrict__ Rm,      // [B,N,3,3]
    const float* __restrict__ Tv,      // [B,N,3]
    const float* __restrict__ fv,      // [B,N,2]
    const float* __restrict__ cv,      // [B,N,2]
    const float* __restrict__ trans,   // [B,N,2,3]
    const float* __restrict__ whv,     // [B,N,2]
    const float* __restrict__ gcv,     // [B,3]
    float* __restrict__ out)           // fused [B,J,P] then grids [B,P,3]
{
    int t = blockIdx.x * blockDim.x + threadIdx.x;
    if (t >= BB * PP) return;
    int b = t / PP;
    int p = t - b * PP;
    int ix  = p / (CBY * CBZ);
    int rem = p - ix * (CBY * CBZ);
    int iy  = rem / CBZ;
    int iz  = rem - iy * CBZ;

    const float stx = 8000.0f / (CBX - 1);
    const float sty = 8000.0f / (CBY - 1);
    const float stz = 2000.0f / (CBZ - 1);
    float gx = -4000.0f + (float)ix * stx + gcv[b * 3 + 0];
    float gy = -4000.0f + (float)iy * sty + gcv[b * 3 + 1];
    float gz = -1000.0f + (float)iz * stz + gcv[b * 3 + 2];

    // grids output (second tuple element)
    {
        float* grids_out = out + (size_t)BB * JJ * PP;
        size_t gb = (size_t)(b * PP + p) * 3;
        grids_out[gb + 0] = gx;
        grids_out[gb + 1] = gy;
        grids_out[gb + 2] = gz;
    }

    // Per-view pair-gather state: two row base offsets + 4 pair coefficients
    float wl0[NN], wr0[NN], wl1[NN], wr1[NN];   // e0/e1 coeffs for row0, row1
    int   r0[NN], r1[NN];                       // row base offsets (in floats)
    float bnd[NN];
    float sumb = 0.0f;

    #pragma unroll
    for (int n = 0; n < NN; ++n) {
        int bn = b * NN + n;
        const float* R = Rm + bn * 9;
        float dx = gx - Tv[bn * 3 + 0];
        float dy = gy - Tv[bn * 3 + 1];
        float dz = gz - Tv[bn * 3 + 2];
        float cx = R[0] * dx + R[1] * dy + R[2] * dz;
        float cy = R[3] * dx + R[4] * dy + R[5] * dz;
        float cz = R[6] * dx + R[7] * dy + R[8] * dz;
        float inv = 1.0f / cz;
        float px = cx * inv * fv[bn * 2 + 0] + cv[bn * 2 + 0];
        float py = cy * inv * fv[bn * 2 + 1] + cv[bn * 2 + 1];
        float w = whv[bn * 2 + 0], h = whv[bn * 2 + 1];
        float bound = (px >= 0.0f && py >= 0.0f && px < w && py < h) ? 1.0f : 0.0f;
        float mwh = fmaxf(w, h);
        px = fminf(fmaxf(px, -1.0f), mwh);
        py = fminf(fmaxf(py, -1.0f), mwh);
        const float* tr = trans + bn * 6;
        float tx = tr[0] * px + tr[1] * py + tr[2];
        float ty = tr[3] * px + tr[4] * py + tr[5];
        tx *= (float)WHH / IMGW;   // 0.25
        ty *= (float)HHH / IMGH;   // 0.25
        float sgx = tx / (float)(WHH - 1) * 2.0f - 1.0f;
        float sgy = ty / (float)(HHH - 1) * 2.0f - 1.0f;
        sgx = fminf(fmaxf(sgx, -1.1f), 1.1f);
        sgy = fminf(fmaxf(sgy, -1.1f), 1.1f);
        float xx = (sgx + 1.0f) * 0.5f * (float)(WHH - 1);
        float yy = (sgy + 1.0f) * 0.5f * (float)(HHH - 1);
        float x0f = floorf(xx), y0f = floorf(yy);
        float wx = xx - x0f, wy = yy - y0f;
        int x0 = (int)x0f, y0 = (int)y0f;

        // x-direction pair coefficients for the aligned-at-xb float2 window.
        // xb = clamp(x0, 0, W-2); window elements e0=img[xb], e1=img[xb+1].
        // normal (0<=x0<=W-2): taps (e0,e1) with ((1-wx), wx)
        // x0 >= W-1: ref uses img[W-1]=e1 for tap0 (vx0 = x0<=W-1), tap1 invalid
        // x0 <  0  : ref uses img[0]=e0 for tap1 (vx1 = x0+1>=0), tap0 invalid
        float axl, axr;
        if (x0 < 0) {
            float vx1 = (x0 + 1 >= 0) ? 1.0f : 0.0f;   // x0 == -1 only
            axl = wx * vx1;
            axr = 0.0f;
        } else if (x0 >= WHH - 1) {
            float vx0 = (x0 <= WHH - 1) ? 1.0f : 0.0f; // x0 == W-1 only
            axl = 0.0f;
            axr = (1.0f - wx) * vx0;
        } else {
            axl = 1.0f - wx;
            axr = wx;
        }
        int xb = min(max(x0, 0), WHH - 2);

        float vy0 = (y0 >= 0 && y0 <= HHH - 1) ? 1.0f : 0.0f;
        float vy1 = (y0 + 1 >= 0 && y0 + 1 <= HHH - 1) ? 1.0f : 0.0f;
        int yc0 = min(max(y0, 0), HHH - 1);
        int yc1 = min(max(y0 + 1, 0), HHH - 1);
        float ay0 = (1.0f - wy) * vy0 * bound;
        float ay1 = wy * vy1 * bound;

        wl0[n] = axl * ay0;  wr0[n] = axr * ay0;
        wl1[n] = axl * ay1;  wr1[n] = axr * ay1;
        r0[n] = yc0 * WHH + xb;
        r1[n] = yc1 * WHH + xb;
        bnd[n] = bound;
        sumb += bound;
    }

    float acc[JJ];
    #pragma unroll
    for (int j = 0; j < JJ; ++j) acc[j] = 0.0f;

    // n outer (one wave-coherent branch per view), j inner (30 independent
    // float2 loads per branch body -> deep memory-level parallelism).
    #pragma unroll
    for (int n = 0; n < NN; ++n) {
        if (bnd[n] != 0.0f) {
            const float* base = hm + (size_t)((n * BB + b) * JJ) * HW;
            float c00 = wl0[n], c01 = wr0[n], c10 = wl1[n], c11 = wr1[n];
            int o0 = r0[n], o1 = r1[n];
            #pragma unroll
            for (int j = 0; j < JJ; ++j) {
                const float* pj = base + j * HW;
                float2 e = *reinterpret_cast<const float2*>(pj + o0);
                float2 f2 = *reinterpret_cast<const float2*>(pj + o1);
                acc[j] += c00 * e.x + c01 * e.y + c10 * f2.x + c11 * f2.y;
            }
        }
    }

    float denom = 1.0f / (sumb + 1e-6f);
    size_t outb = (size_t)b * JJ * PP + p;
    #pragma unroll
    for (int j = 0; j < JJ; ++j) {
        float v = acc[j] * denom;
        v = fminf(fmaxf(v, 0.0f), 1.0f);
        out[outb + (size_t)j * PP] = v;
    }
}

extern "C" void kernel_launch(void* const* d_in, const int* in_sizes, int n_in,
                              void* d_out, int out_size, void* d_ws, size_t ws_size,
                              hipStream_t stream) {
    const float* hm    = (const float*)d_in[0];
    const float* Rm    = (const float*)d_in[1];
    const float* Tv    = (const float*)d_in[2];
    const float* fv    = (const float*)d_in[3];
    const float* cv    = (const float*)d_in[4];
    const float* trans = (const float*)d_in[5];
    const float* whv   = (const float*)d_in[6];
    const float* gcv   = (const float*)d_in[7];
    float* out = (float*)d_out;

    int total = BB * PP;
    int block = 256;
    int grid  = (total + block - 1) / block;
    project_kernel<<<grid, block, 0, stream>>>(hm, Rm, Tv, fv, cv, trans, whv, gcv, out);
}